// Round 1
// baseline (227.942 us; speedup 1.0000x reference)
//
#include <hip/hip_runtime.h>
#include <math.h>

#define CIN   1024
#define S_TOT 400          // F*F = 20*20
#define COUT  255          // A*C = 3*85
#define NCH   85
#define NIMG  64
#define BK    32
#define BCO   64
#define BS    64

__device__ __forceinline__ float sigmoidf_(float v) {
    return 1.0f / (1.0f + expf(-v));
}

__global__ __launch_bounds__(256) void yolo_head_f32(
    const float* __restrict__ xin,
    const float* __restrict__ w,
    const float* __restrict__ bias,
    float* __restrict__ out)
{
    __shared__ float Xs[BK][BS + 4];   // row stride 68 floats = 272B (16B aligned)
    __shared__ float Ws[BK][BCO + 4];  // W tile stored transposed: Ws[k][co_local]

    const int n       = blockIdx.z;
    const int co_base = blockIdx.y * BCO;
    const int s_base  = blockIdx.x * BS;

    const int tid = threadIdx.x;
    const int tx  = tid & 15;   // spatial group (4 s each)
    const int ty  = tid >> 4;   // channel group (4 co each)

    float acc[4][4] = {};

    const float* xin_n = xin + (size_t)n * (CIN * S_TOT);

    for (int k0 = 0; k0 < CIN; k0 += BK) {
        // ---- stage X tile: Xs[k][s_local], 32x64 floats, float4 per thread x2
        #pragma unroll
        for (int i = 0; i < 2; ++i) {
            int slot = tid + i * 256;
            int kk = slot >> 4;            // 0..31
            int sj = (slot & 15) << 2;     // 0..60
            int s  = s_base + sj;
            const float* src = xin_n + (k0 + kk) * S_TOT + s;
            float4 v;
            if (s + 3 < S_TOT) {
                v = *(const float4*)src;
            } else {
                v.x = (s + 0 < S_TOT) ? src[0] : 0.0f;
                v.y = (s + 1 < S_TOT) ? src[1] : 0.0f;
                v.z = (s + 2 < S_TOT) ? src[2] : 0.0f;
                v.w = (s + 3 < S_TOT) ? src[3] : 0.0f;
            }
            *(float4*)&Xs[kk][sj] = v;
        }
        // ---- stage W tile transposed: Ws[k][co_local], coalesced float4 along ci
        #pragma unroll
        for (int i = 0; i < 2; ++i) {
            int slot = tid + i * 256;
            int cl = slot >> 3;            // 0..63
            int kj = (slot & 7) << 2;      // 0..28
            int co = co_base + cl;
            float4 v = make_float4(0.f, 0.f, 0.f, 0.f);
            if (co < COUT)
                v = *(const float4*)(w + (size_t)co * CIN + k0 + kj);
            Ws[kj + 0][cl] = v.x;
            Ws[kj + 1][cl] = v.y;
            Ws[kj + 2][cl] = v.z;
            Ws[kj + 3][cl] = v.w;
        }
        __syncthreads();

        #pragma unroll
        for (int k = 0; k < BK; ++k) {
            float4 xv = *(const float4*)&Xs[k][tx << 2];
            float4 wv = *(const float4*)&Ws[k][ty << 2];
            acc[0][0] = fmaf(wv.x, xv.x, acc[0][0]);
            acc[0][1] = fmaf(wv.x, xv.y, acc[0][1]);
            acc[0][2] = fmaf(wv.x, xv.z, acc[0][2]);
            acc[0][3] = fmaf(wv.x, xv.w, acc[0][3]);
            acc[1][0] = fmaf(wv.y, xv.x, acc[1][0]);
            acc[1][1] = fmaf(wv.y, xv.y, acc[1][1]);
            acc[1][2] = fmaf(wv.y, xv.z, acc[1][2]);
            acc[1][3] = fmaf(wv.y, xv.w, acc[1][3]);
            acc[2][0] = fmaf(wv.z, xv.x, acc[2][0]);
            acc[2][1] = fmaf(wv.z, xv.y, acc[2][1]);
            acc[2][2] = fmaf(wv.z, xv.z, acc[2][2]);
            acc[2][3] = fmaf(wv.z, xv.w, acc[2][3]);
            acc[3][0] = fmaf(wv.w, xv.x, acc[3][0]);
            acc[3][1] = fmaf(wv.w, xv.y, acc[3][1]);
            acc[3][2] = fmaf(wv.w, xv.z, acc[3][2]);
            acc[3][3] = fmaf(wv.w, xv.w, acc[3][3]);
        }
        __syncthreads();
    }

    // ---- fused YOLO epilogue ----
    // anchors / STRIDE, times-32 folded where possible
    const float anch[6] = {3.625f, 2.8125f, 4.875f, 6.1875f, 11.65625f, 10.1875f};

    #pragma unroll
    for (int i = 0; i < 4; ++i) {
        int co = co_base + (ty << 2) + i;
        if (co >= COUT) continue;
        int a = co / NCH;
        int c = co - a * NCH;
        float b = bias[co];
        float ax32_0 = anch[a * 2 + 0] * 32.0f;
        float ax32_1 = anch[a * 2 + 1] * 32.0f;
        #pragma unroll
        for (int j = 0; j < 4; ++j) {
            int s = s_base + (tx << 2) + j;
            if (s >= S_TOT) continue;
            float v = acc[i][j] + b;
            float r;
            if (c == 0)      r = (sigmoidf_(v) + (float)(s % 20)) * 32.0f;
            else if (c == 1) r = (sigmoidf_(v) + (float)(s / 20)) * 32.0f;
            else if (c == 2) r = expf(v) * ax32_0;
            else if (c == 3) r = expf(v) * ax32_1;
            else             r = sigmoidf_(v);
            out[(((size_t)n * 3 + a) * S_TOT + s) * NCH + c] = r;
        }
    }
}

extern "C" void kernel_launch(void* const* d_in, const int* in_sizes, int n_in,
                              void* d_out, int out_size, void* d_ws, size_t ws_size,
                              hipStream_t stream) {
    const float* xin  = (const float*)d_in[0];
    const float* w    = (const float*)d_in[1];
    const float* bias = (const float*)d_in[2];
    float* out = (float*)d_out;

    dim3 grid((S_TOT + BS - 1) / BS, (COUT + BCO - 1) / BCO, NIMG);
    yolo_head_f32<<<grid, 256, 0, stream>>>(xin, w, bias, out);
}

// Round 3
// 74.026 us; speedup vs baseline: 3.0792x; 3.0792x over previous
//
#include <hip/hip_runtime.h>
#include <hip/hip_bf16.h>
#include <math.h>

#define CIN    1024
#define S_TOT  400
#define COUT   255
#define NCH    85
#define NIMG   64
#define BM     256
#define BN     80
#define BK     64
#define NSTEP  (CIN / BK)     // 16
#define NTHR   512

// LDS layout: Ws (256 co x 64 k bf16, swizzled) = 32768 B at 0
//             Xs (80 s   x 64 k bf16, swizzled) = 10240 B at 32768
#define XS_BASE   32768
#define LDS_BYTES (32768 + 10240)
#define WSTEP_B   32768        // bytes of one pre-swizzled W K-step tile (256co x 64k x 2B)

typedef __attribute__((ext_vector_type(8))) short bf16x8;
typedef __attribute__((ext_vector_type(4))) float f32x4;

// byte offset of 16B granule (co, kg) in Ws. row stride 128B; XOR-swizzle by co.
__device__ __forceinline__ int wOff(int co, int kg) {
    return (co << 7) + ((kg << 4) ^ ((co & 7) << 4));
}
// byte offset of 16B granule (s, kg) in Xs. swizzle by (s>>1): free for both
// stride-2 row writes (staging) and stride-1 row reads (B-frags).
__device__ __forceinline__ int xOff(int s, int kg) {
    return XS_BASE + (s << 7) + ((kg << 4) ^ (((s >> 1) & 7) << 4));
}

__device__ __forceinline__ unsigned pk2(float a, float b) {
    __hip_bfloat162 h;
    h.x = __float2bfloat16(a);
    h.y = __float2bfloat16(b);
    return *reinterpret_cast<unsigned*>(&h);
}

__device__ __forceinline__ float sigmoidf_(float v) {
    return 1.0f / (1.0f + expf(-v));
}

__device__ __forceinline__ void gload_lds16(const void* g, void* l) {
    __builtin_amdgcn_global_load_lds(
        (const __attribute__((address_space(1))) unsigned int*)g,
        (__attribute__((address_space(3))) unsigned int*)l,
        16, 0, 0);
}

// ---- pre-kernel: W fp32 -> bf16, laid out exactly as the GEMM's LDS tiles ----
// one thread per 16B output granule: 256 co x 128 granules = 32768 threads
__global__ __launch_bounds__(256) void w_pre(const float* __restrict__ w,
                                             unsigned short* __restrict__ wbf) {
    int g = blockIdx.x * 256 + threadIdx.x;
    int co    = g >> 7;        // 0..255
    int kgAll = g & 127;       // 16B granule within the 1024-k row
    int k     = kgAll << 3;
    int step  = k >> 6;
    int kg    = (k >> 3) & 7;
    union { unsigned short u[8]; bf16x8 v; } pk;
    if (co < COUT) {
        const float* src = w + co * CIN + k;
        #pragma unroll
        for (int j = 0; j < 8; ++j) {
            __hip_bfloat16 h = __float2bfloat16(src[j]);
            pk.u[j] = *reinterpret_cast<unsigned short*>(&h);
        }
    } else {
        #pragma unroll
        for (int j = 0; j < 8; ++j) pk.u[j] = 0;   // pad row 255
    }
    char* dst = reinterpret_cast<char*>(wbf) + step * WSTEP_B + wOff(co, kg);
    *reinterpret_cast<bf16x8*>(dst) = pk.v;
}

// ---- main kernel: 8 waves, BM=256 (all co) x BN=80 s-tile, BK=64 ----
__global__ __launch_bounds__(NTHR) void yolo_mfma(
    const float* __restrict__ xin,
    const unsigned short* __restrict__ wbf,   // pre-swizzled bf16 W
    const float* __restrict__ bias,
    float* __restrict__ out)
{
    __shared__ __align__(16) char smem[LDS_BYTES];

    const int n     = blockIdx.y;
    const int sbase = blockIdx.x * BN;
    const int tid   = threadIdx.x;
    const int lane  = tid & 63;
    const int wid   = tid >> 6;

    const float* xin_n = xin + (size_t)n * (CIN * S_TOT);

    // X staging role: threads 0..319 (waves 0-4), each owns (kg, s-pair)
    const bool xstage = tid < 320;
    const int  sp = tid % 40;            // s-pair index 0..39
    const int  kg = tid / 40;            // k granule 0..7
    const int  s0 = sp * 2;              // even local s
    const float* xsrc0 = xin_n + (kg * 8) * S_TOT + sbase + s0;

    f32x4 acc[2][5] = {};

    float2 cur[8], nxt[8];
    if (xstage) {
        #pragma unroll
        for (int j = 0; j < 8; ++j) cur[j] = *(const float2*)(xsrc0 + j * S_TOT);
    }

    const int co_w = wid * 32;
    const int llo  = lane & 15;
    const int lhi  = lane >> 4;

    for (int t = 0; t < NSTEP; ++t) {
        // --- stage W via global_load_lds: 4 x (512 thr x 16B) = 32768 B ---
        const char* wg = (const char*)wbf + (size_t)t * WSTEP_B;
        #pragma unroll
        for (int i = 0; i < 4; ++i) {
            gload_lds16(wg + i * 8192 + (size_t)tid * 16,
                        smem + i * 8192 + wid * 1024);
        }

        // --- stage X: cvt+pack regs (loaded last iter) -> swizzled LDS ---
        if (xstage) {
            union { unsigned u[4]; bf16x8 v; } r0, r1;
            #pragma unroll
            for (int j = 0; j < 4; ++j) {
                r0.u[j] = pk2(cur[2 * j].x, cur[2 * j + 1].x);
                r1.u[j] = pk2(cur[2 * j].y, cur[2 * j + 1].y);
            }
            *(bf16x8*)(smem + xOff(s0,     kg)) = r0.v;
            *(bf16x8*)(smem + xOff(s0 + 1, kg)) = r1.v;
        }
        __syncthreads();

        // --- prefetch next step's X into regs; flies during MFMA phase ---
        if (t + 1 < NSTEP && xstage) {
            const float* src = xsrc0 + (t + 1) * BK * S_TOT;
            #pragma unroll
            for (int j = 0; j < 8; ++j) nxt[j] = *(const float2*)(src + j * S_TOT);
        }

        // --- MFMA: wave-tile 32co x 80s, 2 K-subtiles ---
        #pragma unroll
        for (int ks = 0; ks < 2; ++ks) {
            const int kgr = ks * 4 + lhi;
            bf16x8 a0 = *(bf16x8*)(smem + wOff(co_w + llo,      kgr));
            bf16x8 a1 = *(bf16x8*)(smem + wOff(co_w + 16 + llo, kgr));
            #pragma unroll
            for (int ni = 0; ni < 5; ++ni) {
                bf16x8 b = *(bf16x8*)(smem + xOff(ni * 16 + llo, kgr));
                acc[0][ni] = __builtin_amdgcn_mfma_f32_16x16x32_bf16(a0, b, acc[0][ni], 0, 0, 0);
                acc[1][ni] = __builtin_amdgcn_mfma_f32_16x16x32_bf16(a1, b, acc[1][ni], 0, 0, 0);
            }
        }
        __syncthreads();

        if (xstage) {
            #pragma unroll
            for (int j = 0; j < 8; ++j) cur[j] = nxt[j];
        }
    }

    // ---- fused YOLO epilogue ----
    const float anchW[3] = {116.0f, 156.0f, 373.0f};   // exp(wh) * anchor  (32s cancel)
    const float anchH[3] = {90.0f, 198.0f, 326.0f};

    #pragma unroll
    for (int mi = 0; mi < 2; ++mi) {
        #pragma unroll
        for (int r = 0; r < 4; ++r) {
            int co = co_w + mi * 16 + lhi * 4 + r;
            if (co < COUT) {
                int a = co / NCH;
                int c = co - a * NCH;
                float bv = bias[co];
                #pragma unroll
                for (int ni = 0; ni < 5; ++ni) {
                    int s = sbase + ni * 16 + llo;
                    float v = acc[mi][ni][r] + bv;
                    float res;
                    if (c == 0)      res = (sigmoidf_(v) + (float)(s % 20)) * 32.0f;
                    else if (c == 1) res = (sigmoidf_(v) + (float)(s / 20)) * 32.0f;
                    else if (c == 2) res = expf(v) * anchW[a];
                    else if (c == 3) res = expf(v) * anchH[a];
                    else             res = sigmoidf_(v);
                    out[(size_t)n * 102000 + a * 34000 + s * 85 + c] = res;
                }
            }
        }
    }
}

extern "C" void kernel_launch(void* const* d_in, const int* in_sizes, int n_in,
                              void* d_out, int out_size, void* d_ws, size_t ws_size,
                              hipStream_t stream) {
    const float* xin  = (const float*)d_in[0];
    const float* w    = (const float*)d_in[1];
    const float* bias = (const float*)d_in[2];
    float* out = (float*)d_out;
    unsigned short* wbf = (unsigned short*)d_ws;   // needs 16 * 32768 = 512 KiB

    w_pre<<<128, 256, 0, stream>>>(w, wbf);
    yolo_mfma<<<dim3(S_TOT / BN, NIMG), NTHR, 0, stream>>>(xin, wbf, bias, out);
}

// Round 4
// 70.046 us; speedup vs baseline: 3.2542x; 1.0568x over previous
//
#include <hip/hip_runtime.h>
#include <hip/hip_bf16.h>
#include <math.h>

#define CIN    1024
#define S_TOT  400
#define COUT   255
#define NCH    85
#define NIMG   64
#define BN     80
#define BK     64
#define NSTEP  16            // CIN / BK
#define NTHR   512

// LDS: Wb0 [0,32768) | Wb1 [32768,65536) | Xs [65536, 65536+10240)
#define WB0      0
#define WB1      32768
#define XS_BASE  65536
#define LDS_BYTES (65536 + 10240)
#define WSTEP_B  32768       // one pre-swizzled W K-step tile: 256co x 64k x 2B

typedef __attribute__((ext_vector_type(8))) short bf16x8;
typedef __attribute__((ext_vector_type(4))) float f32x4;

// byte offset of 16B granule (co, kg) within one W buffer. row stride 128B.
__device__ __forceinline__ int wOff(int co, int kg) {
    return (co << 7) + ((kg << 4) ^ ((co & 7) << 4));
}
// byte offset of 16B granule (s, kg) in Xs; swizzle by (s>>1) — free 2-way for
// stride-2 row writes (staging) and stride-1 row reads (B-frags).
__device__ __forceinline__ int xOff(int s, int kg) {
    return XS_BASE + (s << 7) + ((kg << 4) ^ (((s >> 1) & 7) << 4));
}

__device__ __forceinline__ unsigned pk2(float a, float b) {
    __hip_bfloat162 h;
    h.x = __float2bfloat16(a);
    h.y = __float2bfloat16(b);
    return *reinterpret_cast<unsigned*>(&h);
}

__device__ __forceinline__ float sigmoidf_(float v) {
    return 1.0f / (1.0f + expf(-v));
}

__device__ __forceinline__ void gload_lds16(const void* g, void* l) {
    __builtin_amdgcn_global_load_lds(
        (const __attribute__((address_space(1))) unsigned int*)g,
        (__attribute__((address_space(3))) unsigned int*)l,
        16, 0, 0);
}

// ---- pre-kernel: W fp32 -> bf16, laid out exactly as the GEMM's LDS tiles ----
__global__ __launch_bounds__(256) void w_pre(const float* __restrict__ w,
                                             unsigned short* __restrict__ wbf) {
    int g = blockIdx.x * 256 + threadIdx.x;
    int co    = g >> 7;
    int kgAll = g & 127;
    int k     = kgAll << 3;
    int step  = k >> 6;
    int kg    = (k >> 3) & 7;
    union { unsigned short u[8]; bf16x8 v; } pk;
    if (co < COUT) {
        const float* src = w + co * CIN + k;
        #pragma unroll
        for (int j = 0; j < 8; ++j) {
            __hip_bfloat16 h = __float2bfloat16(src[j]);
            pk.u[j] = *reinterpret_cast<unsigned short*>(&h);
        }
    } else {
        #pragma unroll
        for (int j = 0; j < 8; ++j) pk.u[j] = 0;
    }
    char* dst = reinterpret_cast<char*>(wbf) + step * WSTEP_B + wOff(co, kg);
    *reinterpret_cast<bf16x8*>(dst) = pk.v;
}

// one pipelined phase. CURB/NXTB = compile-time W buffer bases; RC = X reg set
// (holds data for step T, reloaded for step T+2). Waits: vmcnt(20) keeps the
// 8 X(t+1) + 4 W(t+1) + 8 X(t+2) newest ops in flight, drains only W(t).
#define PHASE(T, CURB, NXTB, RC)                                               \
  {                                                                            \
    __builtin_amdgcn_sched_barrier(0);                                         \
    const int tn  = ((T) + 1 < NSTEP) ? (T) + 1 : NSTEP - 1;                   \
    const int tn2 = ((T) + 2 < NSTEP) ? (T) + 2 : NSTEP - 1;                   \
    const char* wg_ = (const char*)wbf + (size_t)tn * WSTEP_B;                 \
    _Pragma("unroll")                                                          \
    for (int i = 0; i < 4; ++i)                                                \
      gload_lds16(wg_ + i * 8192 + (size_t)tid * 16,                           \
                  smem + (NXTB) + i * 8192 + wid * 1024);                      \
    __builtin_amdgcn_sched_barrier(0);                                         \
    if (xstage) {                                                              \
      union { unsigned u[4]; bf16x8 v; } r0_, r1_;                             \
      _Pragma("unroll")                                                        \
      for (int j = 0; j < 4; ++j) {                                            \
        r0_.u[j] = pk2(RC[2 * j].x, RC[2 * j + 1].x);                          \
        r1_.u[j] = pk2(RC[2 * j].y, RC[2 * j + 1].y);                          \
      }                                                                        \
      *(bf16x8*)(smem + xOff(s0, kg))     = r0_.v;                             \
      *(bf16x8*)(smem + xOff(s0 + 1, kg)) = r1_.v;                             \
      const float* xs_ = xsrc0 + (size_t)tn2 * (BK * S_TOT);                   \
      _Pragma("unroll")                                                        \
      for (int j = 0; j < 8; ++j) RC[j] = *(const float2*)(xs_ + j * S_TOT);   \
    }                                                                          \
    asm volatile("s_waitcnt lgkmcnt(0)" ::: "memory");                         \
    if (xstage) asm volatile("s_waitcnt vmcnt(20)" ::: "memory");              \
    else        asm volatile("s_waitcnt vmcnt(4)"  ::: "memory");              \
    __builtin_amdgcn_s_barrier();                                              \
    __builtin_amdgcn_sched_barrier(0);                                         \
    _Pragma("unroll")                                                          \
    for (int ks = 0; ks < 2; ++ks) {                                           \
      const int kgr = ks * 4 + lhi;                                            \
      bf16x8 a0 = *(bf16x8*)(smem + (CURB) + wOff(co_w + llo,      kgr));      \
      bf16x8 a1 = *(bf16x8*)(smem + (CURB) + wOff(co_w + 16 + llo, kgr));      \
      _Pragma("unroll")                                                        \
      for (int ni = 0; ni < 5; ++ni) {                                         \
        bf16x8 b = *(bf16x8*)(smem + xOff(ni * 16 + llo, kgr));                \
        acc[0][ni] = __builtin_amdgcn_mfma_f32_16x16x32_bf16(a0, b, acc[0][ni], 0, 0, 0); \
        acc[1][ni] = __builtin_amdgcn_mfma_f32_16x16x32_bf16(a1, b, acc[1][ni], 0, 0, 0); \
      }                                                                        \
    }                                                                          \
    __builtin_amdgcn_sched_barrier(0);                                         \
    __builtin_amdgcn_s_barrier();                                              \
  }

__global__ __launch_bounds__(NTHR, 4) void yolo_mfma(
    const float* __restrict__ xin,
    const unsigned short* __restrict__ wbf,
    const float* __restrict__ bias,
    float* __restrict__ out)
{
    __shared__ __align__(16) char smem[LDS_BYTES];

    const int n     = blockIdx.y;
    const int sbase = blockIdx.x * BN;
    const int tid   = threadIdx.x;
    const int lane  = tid & 63;
    const int wid   = tid >> 6;

    const float* xin_n = xin + (size_t)n * (CIN * S_TOT);

    const bool xstage = tid < 320;       // waves 0-4 stage X
    const int  sp = tid % 40;
    const int  kg = tid / 40;
    const int  s0 = sp * 2;
    const float* xsrc0 = xin_n + (kg * 8) * S_TOT + sbase + s0;

    f32x4 acc[2][5] = {};

    const int co_w = wid * 32;
    const int llo  = lane & 15;
    const int lhi  = lane >> 4;

    // ---- prologue: pin issue order XE(t0) -> W0 -> XO(t1) ----
    float2 XE[8], XO[8];
    if (xstage) {
        #pragma unroll
        for (int j = 0; j < 8; ++j) XE[j] = *(const float2*)(xsrc0 + j * S_TOT);
    }
    __builtin_amdgcn_sched_barrier(0);
    {
        const char* wg_ = (const char*)wbf;
        #pragma unroll
        for (int i = 0; i < 4; ++i)
            gload_lds16(wg_ + i * 8192 + (size_t)tid * 16,
                        smem + WB0 + i * 8192 + wid * 1024);
    }
    __builtin_amdgcn_sched_barrier(0);
    if (xstage) {
        const float* xs1 = xsrc0 + BK * S_TOT;
        #pragma unroll
        for (int j = 0; j < 8; ++j) XO[j] = *(const float2*)(xs1 + j * S_TOT);
    }

    for (int it = 0; it < NSTEP; it += 2) {
        PHASE(it,     WB0, WB1, XE);
        PHASE(it + 1, WB1, WB0, XO);
    }

    // keep the tail's clamped prefetches alive so steady-state vmcnt counts
    // hold in the last two phases (rule 17: DCE would turn vmcnt(20) into a
    // no-op and race the final W-tile waits)
    if (xstage) {
        #pragma unroll
        for (int j = 0; j < 8; ++j) {
            asm volatile("" :: "v"(XE[j].x), "v"(XE[j].y));
            asm volatile("" :: "v"(XO[j].x), "v"(XO[j].y));
        }
    }

    // ---- fused YOLO epilogue ----
    const float anchW[3] = {116.0f, 156.0f, 373.0f};
    const float anchH[3] = {90.0f, 198.0f, 326.0f};

    #pragma unroll
    for (int mi = 0; mi < 2; ++mi) {
        #pragma unroll
        for (int r = 0; r < 4; ++r) {
            int co = co_w + mi * 16 + lhi * 4 + r;
            if (co < COUT) {
                int a = co / NCH;
                int c = co - a * NCH;
                float bv = bias[co];
                #pragma unroll
                for (int ni = 0; ni < 5; ++ni) {
                    int s = sbase + ni * 16 + llo;
                    float v = acc[mi][ni][r] + bv;
                    float res;
                    if (c == 0)      res = (sigmoidf_(v) + (float)(s % 20)) * 32.0f;
                    else if (c == 1) res = (sigmoidf_(v) + (float)(s / 20)) * 32.0f;
                    else if (c == 2) res = expf(v) * anchW[a];
                    else if (c == 3) res = expf(v) * anchH[a];
                    else             res = sigmoidf_(v);
                    out[(size_t)n * 102000 + a * 34000 + s * 85 + c] = res;
                }
            }
        }
    }
}

extern "C" void kernel_launch(void* const* d_in, const int* in_sizes, int n_in,
                              void* d_out, int out_size, void* d_ws, size_t ws_size,
                              hipStream_t stream) {
    const float* xin  = (const float*)d_in[0];
    const float* w    = (const float*)d_in[1];
    const float* bias = (const float*)d_in[2];
    float* out = (float*)d_out;
    unsigned short* wbf = (unsigned short*)d_ws;   // 16 * 32768 = 512 KiB

    w_pre<<<128, 256, 0, stream>>>(w, wbf);
    yolo_mfma<<<dim3(S_TOT / BN, NIMG), NTHR, 0, stream>>>(xin, wbf, bias, out);
}

// Round 5
// 68.942 us; speedup vs baseline: 3.3063x; 1.0160x over previous
//
#include <hip/hip_runtime.h>
#include <hip/hip_bf16.h>
#include <math.h>

#define CIN    1024
#define S_TOT  400
#define COUT   255
#define NCH    85
#define NIMG   64
#define BN     80
#define BK     64
#define NSTEP  16            // CIN / BK
#define NTHR   256

// LDS: W tile (128 co x 64 k bf16, swizzled) = 16384 B | Xs (80 s x 64 k) = 10240 B
#define XS_BASE   16384
#define LDS_BYTES (16384 + 10240)
#define WSTEP_B   32768      // one pre-swizzled full-256-co W K-step tile in d_ws

typedef __attribute__((ext_vector_type(8))) short bf16x8;
typedef __attribute__((ext_vector_type(4))) float f32x4;

// 16B store type with only 4B alignment guarantee (out stride 85 is odd)
struct __attribute__((aligned(4))) f4u { float x, y, z, w; };

// byte offset of 16B granule (co_local, kg) within the W LDS tile (row 128B).
// co_local & 7 == global co & 7 (co_base is a multiple of 128), so the
// pre-swizzled global tile chunk copies over linearly.
__device__ __forceinline__ int wOff(int co, int kg) {
    return (co << 7) + ((kg << 4) ^ ((co & 7) << 4));
}
// byte offset of 16B granule (s, kg) in Xs; swizzle by (s>>1): 2-way (free) for
// both stride-2-row staging writes and stride-1-row fragment reads.
__device__ __forceinline__ int xOff(int s, int kg) {
    return XS_BASE + (s << 7) + ((kg << 4) ^ (((s >> 1) & 7) << 4));
}

__device__ __forceinline__ unsigned pk2(float a, float b) {
    __hip_bfloat162 h;
    h.x = __float2bfloat16(a);
    h.y = __float2bfloat16(b);
    return *reinterpret_cast<unsigned*>(&h);
}

__device__ __forceinline__ float sigmoidf_(float v) {
    return 1.0f / (1.0f + expf(-v));
}

__device__ __forceinline__ void gload_lds16(const void* g, void* l) {
    __builtin_amdgcn_global_load_lds(
        (const __attribute__((address_space(1))) unsigned int*)g,
        (__attribute__((address_space(3))) unsigned int*)l,
        16, 0, 0);
}

// ---- pre-kernel: W fp32 -> bf16, pre-swizzled into GEMM LDS tile order ----
__global__ __launch_bounds__(256) void w_pre(const float* __restrict__ w,
                                             unsigned short* __restrict__ wbf) {
    int g = blockIdx.x * 256 + threadIdx.x;
    int co    = g >> 7;
    int kgAll = g & 127;
    int k     = kgAll << 3;
    int step  = k >> 6;
    int kg    = (k >> 3) & 7;
    union { unsigned short u[8]; bf16x8 v; } pk;
    if (co < COUT) {
        const float* src = w + co * CIN + k;
        #pragma unroll
        for (int j = 0; j < 8; ++j) {
            __hip_bfloat16 h = __float2bfloat16(src[j]);
            pk.u[j] = *reinterpret_cast<unsigned short*>(&h);
        }
    } else {
        #pragma unroll
        for (int j = 0; j < 8; ++j) pk.u[j] = 0;   // pad row 255
    }
    char* dst = reinterpret_cast<char*>(wbf) + step * WSTEP_B + wOff(co, kg);
    *reinterpret_cast<bf16x8*>(dst) = pk.v;
}

// stage one (s-pair, kg) X unit: 8 float2 rows -> 2 swizzled bf16x8 granules
__device__ __forceinline__ void stageX(const float* base, char* smem, int s0, int kg) {
    float2 cu[8];
    #pragma unroll
    for (int j = 0; j < 8; ++j) cu[j] = *(const float2*)(base + j * S_TOT);
    union { unsigned u[4]; bf16x8 v; } r0, r1;
    #pragma unroll
    for (int j = 0; j < 4; ++j) {
        r0.u[j] = pk2(cu[2 * j].x, cu[2 * j + 1].x);
        r1.u[j] = pk2(cu[2 * j].y, cu[2 * j + 1].y);
    }
    *(bf16x8*)(smem + xOff(s0,     kg)) = r0.v;
    *(bf16x8*)(smem + xOff(s0 + 1, kg)) = r1.v;
}

// ---- main: 4 waves, 128co x 80s tile, 640 blocks for inter-block overlap ----
__global__ __launch_bounds__(NTHR, 4) void yolo_mfma(
    const float* __restrict__ xin,
    const unsigned short* __restrict__ wbf,
    const float* __restrict__ bias,
    float* __restrict__ out)
{
    __shared__ __align__(16) char smem[LDS_BYTES];

    const int n     = blockIdx.z;
    const int cob   = blockIdx.y * 128;
    const int sbase = blockIdx.x * BN;
    const int tid   = threadIdx.x;
    const int lane  = tid & 63;
    const int wid   = tid >> 6;

    const float* xin_n = xin + (size_t)n * (CIN * S_TOT);

    // X staging units: unit u = kg*40 + sp (kg 0..7, s-pair sp 0..39); 320 units
    // over 256 threads -> threads 0..63 take a second unit.
    const int kg0 = tid / 40;
    const int sp0 = tid % 40;
    const int kg1 = (256 + tid) / 40;
    const int sp1 = (256 + tid) % 40;
    const bool dual = tid < 64;

    f32x4 acc[2][5] = {};

    const int co_w = wid * 32;
    const int llo  = lane & 15;
    const int lhi  = lane >> 4;

    for (int t = 0; t < NSTEP; ++t) {
        // --- stage W half-tile via global_load_lds: 4 x (256 thr x 16B) = 16 KB ---
        const char* wg = (const char*)wbf + (size_t)t * WSTEP_B + (size_t)cob * 128;
        #pragma unroll
        for (int i = 0; i < 4; ++i)
            gload_lds16(wg + i * 4096 + (size_t)tid * 16,
                        smem + i * 4096 + wid * 1024);

        // --- stage X: load fp32, cvt+pack, swizzled ds_write ---
        const float* xt = xin_n + (size_t)t * (BK * S_TOT) + sbase;
        stageX(xt + kg0 * 8 * S_TOT + 2 * sp0, smem, 2 * sp0, kg0);
        if (dual)
            stageX(xt + kg1 * 8 * S_TOT + 2 * sp1, smem, 2 * sp1, kg1);

        __syncthreads();   // drains vmcnt(0) (gload) + lgkmcnt

        // --- MFMA: wave-tile 32co x 80s, 2 K-subtiles ---
        #pragma unroll
        for (int ks = 0; ks < 2; ++ks) {
            const int kgr = ks * 4 + lhi;
            bf16x8 a0 = *(bf16x8*)(smem + wOff(co_w + llo,      kgr));
            bf16x8 a1 = *(bf16x8*)(smem + wOff(co_w + 16 + llo, kgr));
            #pragma unroll
            for (int ni = 0; ni < 5; ++ni) {
                bf16x8 b = *(bf16x8*)(smem + xOff(ni * 16 + llo, kgr));
                acc[0][ni] = __builtin_amdgcn_mfma_f32_16x16x32_bf16(a0, b, acc[0][ni], 0, 0, 0);
                acc[1][ni] = __builtin_amdgcn_mfma_f32_16x16x32_bf16(a1, b, acc[1][ni], 0, 0, 0);
            }
        }
        __syncthreads();
    }

    // ---- fused YOLO epilogue; 16B stores (4 consecutive co per fragment) ----
    const float anchW[3] = {116.0f, 156.0f, 373.0f};
    const float anchH[3] = {90.0f, 198.0f, 326.0f};

    #pragma unroll
    for (int mi = 0; mi < 2; ++mi) {
        const int co0 = cob + co_w + mi * 16 + lhi * 4;
        const int aW  = co0 / NCH;
        const int c0  = co0 - aW * NCH;
        const bool whole = (c0 <= NCH - 4) && (co0 + 3 < COUT);
        float bv[4];
        #pragma unroll
        for (int r = 0; r < 4; ++r)
            bv[r] = (co0 + r < COUT) ? bias[co0 + r] : 0.0f;

        #pragma unroll
        for (int ni = 0; ni < 5; ++ni) {
            const int s  = sbase + ni * 16 + llo;
            const float sx = (float)(s % 20);
            const float sy = (float)(s / 20);
            if (whole) {
                float r4[4];
                #pragma unroll
                for (int r = 0; r < 4; ++r) {
                    const int c = c0 + r;
                    const float v = acc[mi][ni][r] + bv[r];
                    float res;
                    if (c == 0)      res = (sigmoidf_(v) + sx) * 32.0f;
                    else if (c == 1) res = (sigmoidf_(v) + sy) * 32.0f;
                    else if (c == 2) res = expf(v) * anchW[aW];
                    else if (c == 3) res = expf(v) * anchH[aW];
                    else             res = sigmoidf_(v);
                    r4[r] = res;
                }
                f4u* p = (f4u*)(out + (size_t)n * 102000 + aW * 34000 + s * 85 + c0);
                f4u val = {r4[0], r4[1], r4[2], r4[3]};
                *p = val;
            } else {
                #pragma unroll
                for (int r = 0; r < 4; ++r) {
                    const int co = co0 + r;
                    if (co < COUT) {
                        const int a2 = co / NCH;
                        const int c  = co - a2 * NCH;
                        const float v = acc[mi][ni][r] + bv[r];
                        float res;
                        if (c == 0)      res = (sigmoidf_(v) + sx) * 32.0f;
                        else if (c == 1) res = (sigmoidf_(v) + sy) * 32.0f;
                        else if (c == 2) res = expf(v) * anchW[a2];
                        else if (c == 3) res = expf(v) * anchH[a2];
                        else             res = sigmoidf_(v);
                        out[(size_t)n * 102000 + a2 * 34000 + s * 85 + c] = res;
                    }
                }
            }
        }
    }
}

extern "C" void kernel_launch(void* const* d_in, const int* in_sizes, int n_in,
                              void* d_out, int out_size, void* d_ws, size_t ws_size,
                              hipStream_t stream) {
    const float* xin  = (const float*)d_in[0];
    const float* w    = (const float*)d_in[1];
    const float* bias = (const float*)d_in[2];
    float* out = (float*)d_out;
    unsigned short* wbf = (unsigned short*)d_ws;   // 16 * 32768 = 512 KiB

    w_pre<<<128, 256, 0, stream>>>(w, wbf);
    yolo_mfma<<<dim3(S_TOT / BN, 2, NIMG), NTHR, 0, stream>>>(xin, wbf, bias, out);
}